// Round 9
// baseline (220.581 us; speedup 1.0000x reference)
//
#include <hip/hip_runtime.h>
#include <hip/hip_bf16.h>

// Problem constants
#define IN_CAPS  1152
#define IN_DIM   8
#define NUM_CAPS 10
#define DIM_CAPS 16
#define B_TOT    256

// pre/final tiling (R3/R4-proven shape: 768 blocks, 2 b/thread)
#define I_T     12                 // i's per block -> 96 i-tiles
#define P_TILES (IN_CAPS / I_T)    // 96
#define B_BLK   32                 // batches per block; 2 per thread

// route_kernel tiling
#define I_S     12                 // i's per block -> 96 i-tiles
#define R_TILES (IN_CAPS / I_S)    // 96
#define RB_BLK  16                 // batches per block; 1 per thread

// ws layout (floats):
//   Vbuf  [256][10][16]            = 40960
//   spart [96][256][10][16]        = 3932160
//   Wt    [1152][16][2][16][4]     = 2359296
//   ubuf  fp8 [256][1152][10][16]  = 47185920 B = 11796480 float-slots
//   total ~72.5 MB
#define VBUF_F  (B_TOT * NUM_CAPS * DIM_CAPS)
#define SPART_F (P_TILES * B_TOT * NUM_CAPS * DIM_CAPS)
#define WT_F    (IN_CAPS * DIM_CAPS * 2 * 16 * 4)

typedef float v2f __attribute__((ext_vector_type(2)));

// Pack 4 floats -> 4 fp8 e4m3 (OCP) in one uint via HW converter.
// fp8 is used ONLY for middle-pass logits (softmax crushes the 3% rel err);
// the final output pass recomputes u_hat in fp32 (R6 lesson: fp8 in the
// final s-accumulation fails threshold by 1%).
__device__ __forceinline__ unsigned pack4_fp8(float a, float b, float c, float d) {
  int w = 0;
  w = __builtin_amdgcn_cvt_pk_fp8_f32(a, b, w, false);  // bytes 0,1
  w = __builtin_amdgcn_cvt_pk_fp8_f32(c, d, w, true);   // bytes 2,3
  return (unsigned)w;
}

// Transpose W[n][i][d][k8] -> Wt[i][d][h][n16][c4]: per-(i,d,h) the 16 n-lanes
// read 16 contiguous float4s (2 fully-consumed lines/wave-instr).
__global__ __launch_bounds__(512) void transpose_kernel(
    const float* __restrict__ W, float* __restrict__ Wt) {
  const int i = blockIdx.x;
  const int t = threadIdx.x;
  const int n = t & 15;
  const int h = (t >> 4) & 1;
  const int d = t >> 5;
  const float4* Wf4 = (const float4*)W;
  float4* Wtf4 = (float4*)Wt;
  float4 v = make_float4(0.f, 0.f, 0.f, 0.f);
  if (n < NUM_CAPS) v = Wf4[((size_t)(n * IN_CAPS + i) * DIM_CAPS + d) * 2 + h];
  Wtf4[(size_t)i * 512 + d * 32 + h * 16 + n] = v;
}

// Compute u_hat once; write fp8 ubuf (logit-grade); fuse routing pass 0
// (V=0 -> c = 1/10 exactly, so s = 0.1 * sum_i u, fp32-exact).
// NOTE: no min-waves in launch_bounds — R1 showed forced occupancy spills.
__global__ __launch_bounds__(256) void pre_kernel(
    const float* __restrict__ x, const float* __restrict__ Wt,
    uint4* __restrict__ ubuf, float* __restrict__ spart) {
  const int tid = threadIdx.x;
  const int n   = tid & 15;
  const int g   = tid >> 4;
  const int b0  = blockIdx.x * B_BLK + 2 * g;
  const int tile = blockIdx.y;
  const int i0  = tile * I_T;
  const bool active = (n < NUM_CAPS);

  float s0[DIM_CAPS], s1[DIM_CAPS];
#pragma unroll
  for (int d = 0; d < DIM_CAPS; ++d) { s0[d] = 0.f; s1[d] = 0.f; }

  const float4* __restrict__ Wtp = (const float4*)Wt;
  const float4* __restrict__ xp  = (const float4*)x;

  for (int i = i0; i < i0 + I_T; ++i) {
    float4 xa0 = xp[(size_t)(b0 * IN_CAPS + i) * 2];
    float4 xb0 = xp[(size_t)(b0 * IN_CAPS + i) * 2 + 1];
    float4 xa1 = xp[(size_t)((b0 + 1) * IN_CAPS + i) * 2];
    float4 xb1 = xp[(size_t)((b0 + 1) * IN_CAPS + i) * 2 + 1];

    const float4* wbase = Wtp + (size_t)i * 512 + n;

    float u0[DIM_CAPS], u1[DIM_CAPS];
#pragma unroll
    for (int d = 0; d < DIM_CAPS; ++d) {
      float4 wa = wbase[d * 32];
      float4 wb = wbase[d * 32 + 16];
      u0[d] = wa.x * xa0.x + wa.y * xa0.y + wa.z * xa0.z + wa.w * xa0.w
            + wb.x * xb0.x + wb.y * xb0.y + wb.z * xb0.z + wb.w * xb0.w;
      u1[d] = wa.x * xa1.x + wa.y * xa1.y + wa.z * xa1.z + wa.w * xa1.w
            + wb.x * xb1.x + wb.y * xb1.y + wb.z * xb1.z + wb.w * xb1.w;
      s0[d] += u0[d];
      s1[d] += u1[d];
    }

    if (active) {
      // ubuf: one uint4 (16 fp8) per (b,i,n)
      size_t ub0 = (size_t)(b0 * IN_CAPS + i) * NUM_CAPS + n;
      size_t ub1 = (size_t)((b0 + 1) * IN_CAPS + i) * NUM_CAPS + n;
      uint4 p;
      p.x = pack4_fp8(u0[0],  u0[1],  u0[2],  u0[3]);
      p.y = pack4_fp8(u0[4],  u0[5],  u0[6],  u0[7]);
      p.z = pack4_fp8(u0[8],  u0[9],  u0[10], u0[11]);
      p.w = pack4_fp8(u0[12], u0[13], u0[14], u0[15]);
      ubuf[ub0] = p;
      p.x = pack4_fp8(u1[0],  u1[1],  u1[2],  u1[3]);
      p.y = pack4_fp8(u1[4],  u1[5],  u1[6],  u1[7]);
      p.z = pack4_fp8(u1[8],  u1[9],  u1[10], u1[11]);
      p.w = pack4_fp8(u1[12], u1[13], u1[14], u1[15]);
      ubuf[ub1] = p;
    }
  }

  if (active) {
    float* sp0 = spart + ((size_t)(tile * B_TOT + b0) * NUM_CAPS + n) * DIM_CAPS;
    float* sp1 = spart + ((size_t)(tile * B_TOT + b0 + 1) * NUM_CAPS + n) * DIM_CAPS;
#pragma unroll
    for (int d = 0; d < DIM_CAPS; ++d) {
      sp0[d] = 0.1f * s0[d];
      sp1[d] = 0.1f * s1[d];
    }
  }
}

// Middle routing sweep over fp8 u_hat (prefetched): bd = u.V, softmax over n,
// s += c*u, partial store. Only feeds V for the next pass — logit-grade
// precision is sufficient (softmax: dOut/du_fp8_err ~ 1e-4).
__global__ __launch_bounds__(256) void route_kernel(
    const uint4* __restrict__ ubuf, const float* __restrict__ Vbuf,
    float* __restrict__ spart) {
  const int tid = threadIdx.x;
  const int n   = tid & 15;
  const int bl  = tid >> 4;
  const int b   = blockIdx.x * RB_BLK + bl;
  const int tile = blockIdx.y;
  const int i0  = tile * I_S;
  const bool active = (n < NUM_CAPS);
  const int nn = active ? n : 0;

  v2f V2[8], s2[8];
  const v2f* vp = (const v2f*)(Vbuf + (b * NUM_CAPS + nn) * DIM_CAPS);
#pragma unroll
  for (int j = 0; j < 8; ++j) { V2[j] = vp[j]; s2[j] = (v2f)(0.f); }

  const uint4* up = ubuf + (size_t)(b * IN_CAPS + i0) * NUM_CAPS + nn;
  uint4 w = up[0];

#pragma unroll
  for (int ii = 0; ii < I_S; ++ii) {
    // prefetch next i (clamped -> always valid, redundant on last iter)
    const int nxt = (ii + 1 < I_S) ? (ii + 1) : ii;
    uint4 p = up[(size_t)nxt * NUM_CAPS];

    v2f u2[8];
    u2[0] = __builtin_amdgcn_cvt_pk_f32_fp8(w.x, false);
    u2[1] = __builtin_amdgcn_cvt_pk_f32_fp8(w.x, true);
    u2[2] = __builtin_amdgcn_cvt_pk_f32_fp8(w.y, false);
    u2[3] = __builtin_amdgcn_cvt_pk_f32_fp8(w.y, true);
    u2[4] = __builtin_amdgcn_cvt_pk_f32_fp8(w.z, false);
    u2[5] = __builtin_amdgcn_cvt_pk_f32_fp8(w.z, true);
    u2[6] = __builtin_amdgcn_cvt_pk_f32_fp8(w.w, false);
    u2[7] = __builtin_amdgcn_cvt_pk_f32_fp8(w.w, true);

    v2f acc = u2[0] * V2[0];
#pragma unroll
    for (int j = 1; j < 8; ++j) acc += u2[j] * V2[j];
    float bd = acc.x + acc.y;

    float e = active ? __expf(bd) : 0.f;
    float es = e;
#pragma unroll
    for (int m = 1; m < 16; m <<= 1) es += __shfl_xor(es, m, 16);
    float c = e / es;
#pragma unroll
    for (int j = 0; j < 8; ++j) s2[j] += c * u2[j];

    w = p;
  }

  if (active) {
    v2f* sp = (v2f*)(spart + ((size_t)(tile * B_TOT + b) * NUM_CAPS + n) * DIM_CAPS);
#pragma unroll
    for (int j = 0; j < 8; ++j) sp[j] = s2[j];
  }
}

// Final pass: recompute u_hat in fp32 from Wt (exact), bd = u.V (V = v1+v2+v3),
// softmax, s-accumulate. Structurally R3's measured-62us pass_kernel.
__global__ __launch_bounds__(256) void final_kernel(
    const float* __restrict__ x, const float* __restrict__ Wt,
    const float* __restrict__ Vbuf, float* __restrict__ spart) {
  const int tid = threadIdx.x;
  const int n   = tid & 15;
  const int g   = tid >> 4;
  const int b0  = blockIdx.x * B_BLK + 2 * g;
  const int tile = blockIdx.y;
  const int i0  = tile * I_T;
  const bool active = (n < NUM_CAPS);
  const int nn = active ? n : 0;

  float V0[DIM_CAPS], V1[DIM_CAPS], s0[DIM_CAPS], s1[DIM_CAPS];
  const float* vp0 = Vbuf + (b0 * NUM_CAPS + nn) * DIM_CAPS;
  const float* vp1 = Vbuf + ((b0 + 1) * NUM_CAPS + nn) * DIM_CAPS;
#pragma unroll
  for (int d = 0; d < DIM_CAPS; ++d) {
    V0[d] = vp0[d]; V1[d] = vp1[d];
    s0[d] = 0.f;    s1[d] = 0.f;
  }

  const float4* __restrict__ Wtp = (const float4*)Wt;
  const float4* __restrict__ xp  = (const float4*)x;

  for (int i = i0; i < i0 + I_T; ++i) {
    float4 xa0 = xp[(size_t)(b0 * IN_CAPS + i) * 2];
    float4 xb0 = xp[(size_t)(b0 * IN_CAPS + i) * 2 + 1];
    float4 xa1 = xp[(size_t)((b0 + 1) * IN_CAPS + i) * 2];
    float4 xb1 = xp[(size_t)((b0 + 1) * IN_CAPS + i) * 2 + 1];

    const float4* wbase = Wtp + (size_t)i * 512 + n;

    float u0[DIM_CAPS], u1[DIM_CAPS];
    float bd0 = 0.f, bd1 = 0.f;
#pragma unroll
    for (int d = 0; d < DIM_CAPS; ++d) {
      float4 wa = wbase[d * 32];
      float4 wb = wbase[d * 32 + 16];
      float a = wa.x * xa0.x + wa.y * xa0.y + wa.z * xa0.z + wa.w * xa0.w
              + wb.x * xb0.x + wb.y * xb0.y + wb.z * xb0.z + wb.w * xb0.w;
      float c = wa.x * xa1.x + wa.y * xa1.y + wa.z * xa1.z + wa.w * xa1.w
              + wb.x * xb1.x + wb.y * xb1.y + wb.z * xb1.z + wb.w * xb1.w;
      u0[d] = a; u1[d] = c;
      bd0 += a * V0[d];
      bd1 += c * V1[d];
    }

    float e0 = active ? __expf(bd0) : 0.f;
    float e1 = active ? __expf(bd1) : 0.f;
    float es0 = e0, es1 = e1;
#pragma unroll
    for (int m = 1; m < 16; m <<= 1) {
      es0 += __shfl_xor(es0, m, 16);
      es1 += __shfl_xor(es1, m, 16);
    }
    float c0 = e0 / es0;
    float c1 = e1 / es1;
#pragma unroll
    for (int d = 0; d < DIM_CAPS; ++d) {
      s0[d] += c0 * u0[d];
      s1[d] += c1 * u1[d];
    }
  }

  if (active) {
    float* sp0 = spart + ((size_t)(tile * B_TOT + b0) * NUM_CAPS + n) * DIM_CAPS;
    float* sp1 = spart + ((size_t)(tile * B_TOT + b0 + 1) * NUM_CAPS + n) * DIM_CAPS;
#pragma unroll
    for (int d = 0; d < DIM_CAPS; ++d) {
      sp0[d] = s0[d];
      sp1[d] = s1[d];
    }
  }
}

// Reduce NT partial tiles -> s; v = squash(s); V += v or out = v.
template <int NT>
__global__ void vupdate_kernel(const float* __restrict__ spart,
                               float* __restrict__ Vbuf,
                               float* __restrict__ out, int is_final) {
  const int b   = blockIdx.x;            // 0..255
  const int t   = threadIdx.x;           // 0..159 : n = t/16, d = t%16
  const int base = b * (NUM_CAPS * DIM_CAPS) + t;
  float s = 0.f;
#pragma unroll 16
  for (int tl = 0; tl < NT; ++tl) {
    s += spart[(size_t)tl * (B_TOT * NUM_CAPS * DIM_CAPS) + base];
  }
  float sq = s * s;
#pragma unroll
  for (int m = 1; m < 16; m <<= 1) sq += __shfl_xor(sq, m, 16);  // sum over d
  float norm = sqrtf(sq);
  float v = s * (sq / (1.f + sq)) / (norm + 1e-8f);
  if (is_final) {
    out[base] = v;
  } else {
    Vbuf[base] += v;
  }
}

extern "C" void kernel_launch(void* const* d_in, const int* in_sizes, int n_in,
                              void* d_out, int out_size, void* d_ws, size_t ws_size,
                              hipStream_t stream) {
  const float* x = (const float*)d_in[0];  // [256,1152,8]
  const float* W = (const float*)d_in[1];  // [1,10,1152,16,8]
  float* out   = (float*)d_out;            // [256,10,16]
  float* Vbuf  = (float*)d_ws;
  float* spart = Vbuf + VBUF_F;
  float* Wt    = spart + SPART_F;
  uint4* ubuf  = (uint4*)(Wt + WT_F);      // 47.2 MB fp8 u_hat (logit-grade)

  // zero V only (spart/ubuf fully written before use)
  hipMemsetAsync(Vbuf, 0, (size_t)VBUF_F * sizeof(float), stream);

  transpose_kernel<<<IN_CAPS, 512, 0, stream>>>(W, Wt);

  // pass 0 fused into u_hat materialization (c == 0.1 exactly when V == 0)
  pre_kernel<<<dim3(B_TOT / B_BLK, P_TILES), 256, 0, stream>>>(x, Wt, ubuf, spart);
  vupdate_kernel<P_TILES><<<B_TOT, NUM_CAPS * DIM_CAPS, 0, stream>>>(spart, Vbuf, out, 0);

  // passes 1,2: fp8 u_hat (feeds logits only)
  for (int p = 1; p < 3; ++p) {
    route_kernel<<<dim3(B_TOT / RB_BLK, R_TILES), 256, 0, stream>>>(ubuf, Vbuf, spart);
    vupdate_kernel<R_TILES><<<B_TOT, NUM_CAPS * DIM_CAPS, 0, stream>>>(spart, Vbuf, out, 0);
  }

  // pass 3 (final): exact fp32 recompute of u_hat
  final_kernel<<<dim3(B_TOT / B_BLK, P_TILES), 256, 0, stream>>>(x, Wt, Vbuf, spart);
  vupdate_kernel<P_TILES><<<B_TOT, NUM_CAPS * DIM_CAPS, 0, stream>>>(spart, Vbuf, out, 1);
}

// Round 10
// 212.431 us; speedup vs baseline: 1.0384x; 1.0384x over previous
//
#include <hip/hip_runtime.h>
#include <hip/hip_bf16.h>

// Problem constants
#define IN_CAPS  1152
#define IN_DIM   8
#define NUM_CAPS 10
#define DIM_CAPS 16
#define B_TOT    256

// pre_kernel tiling (R4-proven: 768 blocks, 62 us)
#define I_T     12                 // i's per block -> 96 i-tiles
#define P_TILES (IN_CAPS / I_T)    // 96
#define B_BLK   32                 // batches per block; 2 per thread

// route_kernel tiling
#define I_S     12                 // i's per block -> 96 i-tiles
#define R_TILES (IN_CAPS / I_S)    // 96
#define RB_BLK  16                 // batches per block; 1 per thread

// spart tile stride: padded +64 floats to break power-of-2 L2-set aliasing
// (R8 post-mortem: 163840-B stride made vupdate's 96 strided loads serialize)
#define SPART_STRIDE (B_TOT * NUM_CAPS * DIM_CAPS + 64)

// ws layout (floats):
//   Vbuf  [256][10][16]            = 40960
//   spart [96][SPART_STRIDE]       = 96*41024
//   Wt    [1152][16][2][16][4]     = 2359296
//   ubuf  bf16 [256][1152][10][16] = 47185920 bf16 = 23592960 float-slots
//   total ~120 MB
#define VBUF_F  (B_TOT * NUM_CAPS * DIM_CAPS)
#define SPART_F (P_TILES * SPART_STRIDE)
#define WT_F    (IN_CAPS * DIM_CAPS * 2 * 16 * 4)

typedef float v2f __attribute__((ext_vector_type(2)));

__device__ __forceinline__ unsigned pack2_bf16(float a, float b) {
  __hip_bfloat162 h = __float22bfloat162_rn(make_float2(a, b));
  return *reinterpret_cast<unsigned*>(&h);
}
__device__ __forceinline__ v2f unpack2_bf16_v(unsigned w) {
  v2f r;
  r.x = __uint_as_float(w << 16);
  r.y = __uint_as_float(w & 0xffff0000u);
  return r;
}

// Transpose W[n][i][d][k8] -> Wt[i][d][h][n16][c4]: per-(i,d,h) the 16 n-lanes
// read 16 contiguous float4s (2 fully-consumed lines/wave-instr).
// Blocks 0..79 also zero Vbuf (replaces a separate memset launch).
__global__ __launch_bounds__(512) void transpose_kernel(
    const float* __restrict__ W, float* __restrict__ Wt,
    float* __restrict__ Vbuf) {
  const int i = blockIdx.x;
  const int t = threadIdx.x;
  if (i < 80) Vbuf[i * 512 + t] = 0.f;   // 80*512 = 40960 = VBUF_F
  const int n = t & 15;
  const int h = (t >> 4) & 1;
  const int d = t >> 5;
  const float4* Wf4 = (const float4*)W;
  float4* Wtf4 = (float4*)Wt;
  float4 v = make_float4(0.f, 0.f, 0.f, 0.f);
  if (n < NUM_CAPS) v = Wf4[((size_t)(n * IN_CAPS + i) * DIM_CAPS + d) * 2 + h];
  Wtf4[(size_t)i * 512 + d * 32 + h * 16 + n] = v;
}

// Compute u_hat once; write bf16 ubuf; fuse routing pass 0 (V=0 -> c = 1/10
// exactly, so s = 0.1 * sum_i u). R4-exact structure (62 us measured).
// NOTE: no min-waves in launch_bounds — R1 showed forced occupancy spills.
__global__ __launch_bounds__(256) void pre_kernel(
    const float* __restrict__ x, const float* __restrict__ Wt,
    uint4* __restrict__ ubuf, float* __restrict__ spart) {
  const int tid = threadIdx.x;
  const int n   = tid & 15;
  const int g   = tid >> 4;
  const int b0  = blockIdx.x * B_BLK + 2 * g;
  const int tile = blockIdx.y;
  const int i0  = tile * I_T;
  const bool active = (n < NUM_CAPS);

  float s0[DIM_CAPS], s1[DIM_CAPS];
#pragma unroll
  for (int d = 0; d < DIM_CAPS; ++d) { s0[d] = 0.f; s1[d] = 0.f; }

  const float4* __restrict__ Wtp = (const float4*)Wt;
  const float4* __restrict__ xp  = (const float4*)x;

  for (int i = i0; i < i0 + I_T; ++i) {
    float4 xa0 = xp[(size_t)(b0 * IN_CAPS + i) * 2];
    float4 xb0 = xp[(size_t)(b0 * IN_CAPS + i) * 2 + 1];
    float4 xa1 = xp[(size_t)((b0 + 1) * IN_CAPS + i) * 2];
    float4 xb1 = xp[(size_t)((b0 + 1) * IN_CAPS + i) * 2 + 1];

    const float4* wbase = Wtp + (size_t)i * 512 + n;

    float u0[DIM_CAPS], u1[DIM_CAPS];
#pragma unroll
    for (int d = 0; d < DIM_CAPS; ++d) {
      float4 wa = wbase[d * 32];
      float4 wb = wbase[d * 32 + 16];
      u0[d] = wa.x * xa0.x + wa.y * xa0.y + wa.z * xa0.z + wa.w * xa0.w
            + wb.x * xb0.x + wb.y * xb0.y + wb.z * xb0.z + wb.w * xb0.w;
      u1[d] = wa.x * xa1.x + wa.y * xa1.y + wa.z * xa1.z + wa.w * xa1.w
            + wb.x * xb1.x + wb.y * xb1.y + wb.z * xb1.z + wb.w * xb1.w;
      s0[d] += u0[d];
      s1[d] += u1[d];
    }

    if (active) {
      // ubuf element index: ((b*1152 + i)*10 + n) * 16 bf16 = *2 uint4
      size_t ub0 = ((size_t)(b0 * IN_CAPS + i) * NUM_CAPS + n) * 2;
      size_t ub1 = ((size_t)((b0 + 1) * IN_CAPS + i) * NUM_CAPS + n) * 2;
      uint4 p0, p1;
      p0.x = pack2_bf16(u0[0], u0[1]);  p0.y = pack2_bf16(u0[2], u0[3]);
      p0.z = pack2_bf16(u0[4], u0[5]);  p0.w = pack2_bf16(u0[6], u0[7]);
      p1.x = pack2_bf16(u0[8], u0[9]);  p1.y = pack2_bf16(u0[10], u0[11]);
      p1.z = pack2_bf16(u0[12], u0[13]); p1.w = pack2_bf16(u0[14], u0[15]);
      ubuf[ub0] = p0; ubuf[ub0 + 1] = p1;
      p0.x = pack2_bf16(u1[0], u1[1]);  p0.y = pack2_bf16(u1[2], u1[3]);
      p0.z = pack2_bf16(u1[4], u1[5]);  p0.w = pack2_bf16(u1[6], u1[7]);
      p1.x = pack2_bf16(u1[8], u1[9]);  p1.y = pack2_bf16(u1[10], u1[11]);
      p1.z = pack2_bf16(u1[12], u1[13]); p1.w = pack2_bf16(u1[14], u1[15]);
      ubuf[ub1] = p0; ubuf[ub1 + 1] = p1;
    }
  }

  if (active) {
    float* sp0 = spart + (size_t)tile * SPART_STRIDE + (b0 * NUM_CAPS + n) * DIM_CAPS;
    float* sp1 = spart + (size_t)tile * SPART_STRIDE + ((b0 + 1) * NUM_CAPS + n) * DIM_CAPS;
#pragma unroll
    for (int d = 0; d < DIM_CAPS; ++d) {
      sp0[d] = 0.1f * s0[d];
      sp1[d] = 0.1f * s1[d];
    }
  }
}

// One routing sweep over materialized bf16 u_hat, software-pipelined:
// prefetch i+1's loads during i's compute. bd = u.V, softmax over n,
// s += c*u, partial store (no atomics).
__global__ __launch_bounds__(256) void route_kernel(
    const uint4* __restrict__ ubuf, const float* __restrict__ Vbuf,
    float* __restrict__ spart) {
  const int tid = threadIdx.x;
  const int n   = tid & 15;
  const int bl  = tid >> 4;
  const int b   = blockIdx.x * RB_BLK + bl;
  const int tile = blockIdx.y;
  const int i0  = tile * I_S;
  const bool active = (n < NUM_CAPS);
  const int nn = active ? n : 0;

  v2f V2[8], s2[8];
  const v2f* vp = (const v2f*)(Vbuf + (b * NUM_CAPS + nn) * DIM_CAPS);
#pragma unroll
  for (int j = 0; j < 8; ++j) { V2[j] = vp[j]; s2[j] = (v2f)(0.f); }

  // base of this thread's i-run; stride per i = NUM_CAPS*2 uint4
  const uint4* up = ubuf + ((size_t)(b * IN_CAPS + i0) * NUM_CAPS + nn) * 2;
  uint4 w0 = up[0];
  uint4 w1 = up[1];

#pragma unroll
  for (int ii = 0; ii < I_S; ++ii) {
    // prefetch next i (clamped -> always valid, redundant on last iter)
    const int nxt = (ii + 1 < I_S) ? (ii + 1) : ii;
    const uint4* upn = up + (size_t)nxt * (NUM_CAPS * 2);
    uint4 p0 = upn[0];
    uint4 p1 = upn[1];

    v2f u2[8];
    u2[0] = unpack2_bf16_v(w0.x); u2[1] = unpack2_bf16_v(w0.y);
    u2[2] = unpack2_bf16_v(w0.z); u2[3] = unpack2_bf16_v(w0.w);
    u2[4] = unpack2_bf16_v(w1.x); u2[5] = unpack2_bf16_v(w1.y);
    u2[6] = unpack2_bf16_v(w1.z); u2[7] = unpack2_bf16_v(w1.w);

    v2f acc = u2[0] * V2[0];
#pragma unroll
    for (int j = 1; j < 8; ++j) acc += u2[j] * V2[j];
    float bd = acc.x + acc.y;

    float e = active ? __expf(bd) : 0.f;
    float es = e;
#pragma unroll
    for (int m = 1; m < 16; m <<= 1) es += __shfl_xor(es, m, 16);
    float c = e / es;
#pragma unroll
    for (int j = 0; j < 8; ++j) s2[j] += c * u2[j];

    w0 = p0; w1 = p1;
  }

  if (active) {
    v2f* sp = (v2f*)(spart + (size_t)tile * SPART_STRIDE + (b * NUM_CAPS + n) * DIM_CAPS);
#pragma unroll
    for (int j = 0; j < 8; ++j) sp[j] = s2[j];
  }
}

// Reduce NT partial tiles -> s; v = squash(s); V += v or out = v.
// R9 rebuild: 640 threads (10 waves), 4 tl-groups x 160 lanes, LDS combine —
// replaces the 160-thread 96-serial-load version (suspected ~28 us each).
template <int NT>
__global__ __launch_bounds__(640) void vupdate_kernel(
    const float* __restrict__ spart, float* __restrict__ Vbuf,
    float* __restrict__ out, int is_final) {
  __shared__ float red[4][160];
  const int b   = blockIdx.x;            // 0..255
  const int t   = threadIdx.x;           // 0..639
  const int grp = t / 160;               // 0..3
  const int idx = t - grp * 160;         // n*16+d
  const int base = b * (NUM_CAPS * DIM_CAPS) + idx;
  float s = 0.f;
#pragma unroll
  for (int tl = grp; tl < NT; tl += 4) {
    s += spart[(size_t)tl * SPART_STRIDE + base];
  }
  red[grp][idx] = s;
  __syncthreads();
  if (grp == 0) {
    s = red[0][idx] + red[1][idx] + red[2][idx] + red[3][idx];
    float sq = s * s;
#pragma unroll
    for (int m = 1; m < 16; m <<= 1) sq += __shfl_xor(sq, m, 16);  // sum over d
    float norm = sqrtf(sq);
    float v = s * (sq / (1.f + sq)) / (norm + 1e-8f);
    if (is_final) {
      out[base] = v;
    } else {
      Vbuf[base] += v;
    }
  }
}

extern "C" void kernel_launch(void* const* d_in, const int* in_sizes, int n_in,
                              void* d_out, int out_size, void* d_ws, size_t ws_size,
                              hipStream_t stream) {
  const float* x = (const float*)d_in[0];  // [256,1152,8]
  const float* W = (const float*)d_in[1];  // [1,10,1152,16,8]
  float* out   = (float*)d_out;            // [256,10,16]
  float* Vbuf  = (float*)d_ws;
  float* spart = Vbuf + VBUF_F;
  float* Wt    = spart + SPART_F;
  uint4* ubuf  = (uint4*)(Wt + WT_F);      // 94.4 MB bf16 u_hat

  // transpose also zeroes Vbuf (spart/ubuf fully written before use)
  transpose_kernel<<<IN_CAPS, 512, 0, stream>>>(W, Wt, Vbuf);

  // pass 0 fused into u_hat materialization (c == 0.1 exactly when V == 0)
  pre_kernel<<<dim3(B_TOT / B_BLK, P_TILES), 256, 0, stream>>>(x, Wt, ubuf, spart);
  vupdate_kernel<P_TILES><<<B_TOT, 640, 0, stream>>>(spart, Vbuf, out, 0);

  // passes 1..3 stream bf16 u_hat
  for (int p = 1; p < 4; ++p) {
    route_kernel<<<dim3(B_TOT / RB_BLK, R_TILES), 256, 0, stream>>>(ubuf, Vbuf, spart);
    vupdate_kernel<R_TILES><<<B_TOT, 640, 0, stream>>>(spart, Vbuf, out, p == 3);
  }
}